// Round 6
// baseline (48462.762 us; speedup 1.0000x reference)
//
#include <hip/hip_runtime.h>

typedef __attribute__((ext_vector_type(4))) float f32x4;

// Static device workspace: 22,513,664 f32 = 90 MB. Module-owned; independent of
// ws_size; not poisoned by the harness. Every region is written before read on
// every call (no reliance on load-time zero-init).
#define OFF_OPS   0L          // [4][1024][1024] f32: S0, 2S0^2-I, S1, 2S1^2-I
#define OFF_WT2   4194304L    // 4 x ([640][128] Wru | [640][64] Wc)
#define OFF_H0    4685824L    // [32*1024][64]
#define OFF_H1    6782976L    // [32*1024][64]
#define OFF_RSUM  8880128L    // [1024]
#define OFF_CSUM  8881152L    // [1024]
#define OFF_D     8882176L    // [16][1024][640]  (batch group of 16)
#define OFF_RU    19367936L   // [16*1024][128]
#define OFF_PC    21465088L   // [16*1024][64]
#define WS_TOTAL  22513664L

__device__ static float G_WS[WS_TOTAL];

// zero H0, H1 (contiguous 4,194,304) and csum (1024)
__global__ __launch_bounds__(256)
void init0_k()
{
    const long i = (long)blockIdx.x * 256 + threadIdx.x;
    if (i < 4194304L) G_WS[OFF_H0 + i] = 0.f;
    else if (i < 4195328L) G_WS[OFF_CSUM + (i - 4194304L)] = 0.f;
}

// C[M,N] = A[M,K] @ B[K,N], all f32, operands inside G_WS (offsets).
// z = (bz<<2)|mat: A += mat*sAm; B += bz*sBb; C += bz*sCb + mat*sCm.
template<bool P2F>
__global__ __launch_bounds__(256)
void sgemm(long Aoff, int lda, long sAm,
           long Boff, int ldb, long sBb,
           long Coff, int ldc, long sCb, long sCm,
           int K)
{
    __shared__ __attribute__((aligned(16))) float As[16][68];   // [k][m]
    __shared__ __attribute__((aligned(16))) float Bs[16][68];   // [k][n]
    const int tid = threadIdx.x;
    const int tm = tid & 15, tn = tid >> 4;
    const int m0 = blockIdx.y * 64, n0 = blockIdx.x * 64;
    const int z = blockIdx.z;
    const int mat = z & 3;
    const long bz = z >> 2;
    const float* A = G_WS + Aoff + (long)mat * sAm;
    const float* B = G_WS + Boff + bz * sBb;

    float acc[4][4] = {};
    const int arow = tid >> 2, akq = (tid & 3) * 4;
    const int brow = tid >> 4, bn4 = (tid & 15) * 4;

    for (int kt = 0; kt < K; kt += 16) {
        __syncthreads();
#pragma unroll
        for (int i = 0; i < 4; ++i)
            As[akq + i][arow] = A[(long)(m0 + arow) * lda + kt + akq + i];
#pragma unroll
        for (int i = 0; i < 4; ++i)
            Bs[brow][bn4 + i] = B[(long)(kt + brow) * ldb + n0 + bn4 + i];
        __syncthreads();
#pragma unroll
        for (int kk = 0; kk < 16; ++kk) {
            const f32x4 av = *(const f32x4*)&As[kk][tm * 4];
            const f32x4 bv = *(const f32x4*)&Bs[kk][tn * 4];
#pragma unroll
            for (int i = 0; i < 4; ++i)
#pragma unroll
                for (int j = 0; j < 4; ++j)
                    acc[i][j] += av[i] * bv[j];
        }
    }

    float* C = G_WS + Coff + bz * sCb + (long)mat * sCm;
#pragma unroll
    for (int i = 0; i < 4; ++i)
#pragma unroll
        for (int j = 0; j < 4; ++j) {
            const int r = m0 + tm * 4 + i, c = n0 + tn * 4 + j;
            float v = acc[i][j];
            if (P2F) v = 2.f * v - (r == c ? 1.f : 0.f);
            C[(long)r * ldc + c] = v;
        }
}

// D[gr][f] (row 640, k0 block) = [x | (r?)*h | zero-pad], f in [0,128)
__global__ __launch_bounds__(256)
void concat_f(const float* __restrict__ xext, long xoff, long xbs, int xd,
              long Hoff, long RUoff, long Doff)
{
    const long idx = (long)blockIdx.x * 256 + threadIdx.x;
    const int f = (int)(idx & 127);
    const long gr = idx >> 7;
    const long bl = gr >> 10, n = gr & 1023;
    const float* x = xext ? xext : (xoff >= 0 ? G_WS + xoff : (const float*)0);
    float v = 0.f;
    if (f < xd) {
        if (x) v = x[bl * xbs + n * xd + f];
    } else if (f < xd + 64) {
        v = G_WS[Hoff + gr * 64 + (f - xd)];
        if (RUoff >= 0) v *= G_WS[RUoff + gr * 128 + (f - xd)];
    }
    G_WS[Doff + gr * 640 + f] = v;
}

__global__ __launch_bounds__(256)
void rowsum_k(const float* __restrict__ adj)
{
    const int r = blockIdx.x, tid = threadIdx.x;
    float s = 0.f;
    for (int c = tid; c < 1024; c += 256) s += adj[(long)r * 1024 + c];
#pragma unroll
    for (int o = 32; o; o >>= 1) s += __shfl_down(s, o, 64);
    __shared__ float ps[4];
    if ((tid & 63) == 0) ps[tid >> 6] = s;
    __syncthreads();
    if (tid == 0) G_WS[OFF_RSUM + r] = ps[0] + ps[1] + ps[2] + ps[3];
}

__global__ __launch_bounds__(256)
void colsum_k(const float* __restrict__ adj)
{
    const int c = blockIdx.x * 256 + threadIdx.x;   // 4 blocks x 256 = 1024 cols
    float s = 0.f;
    for (int r = 0; r < 1024; ++r) s += adj[(long)r * 1024 + c];
    G_WS[OFF_CSUM + c] = s;
}

// OPS[0][m][n] = adj[n][m]/rsum[n]   (support0 = RW(adj)^T)
// OPS[2][m][n] = adj[m][n]/csum[n]   (support1 = RW(adj^T)^T)
__global__ __launch_bounds__(256)
void ops_k(const float* __restrict__ adj)
{
    const int id = blockIdx.x * 256 + threadIdx.x;
    const int m = id >> 10, n = id & 1023;
    G_WS[OFF_OPS + id] = adj[(long)n * 1024 + m] / fmaxf(G_WS[OFF_RSUM + n], 1e-8f);
    G_WS[OFF_OPS + 2 * 1048576L + id] = adj[id] / fmaxf(G_WS[OFF_CSUM + n], 1e-8f);
}

// WT[j][o] (row-major [640][O]) = (fp<F) ? W[(k*F+fp)*O + o] : 0, j = k*128+fp
__global__ __launch_bounds__(256)
void wt2_k(const float* __restrict__ W, long WToff, int O, int F)
{
    const int id = blockIdx.x * 256 + threadIdx.x;
    if (id >= 640 * O) return;
    const int j = id / O, o = id % O;
    const int k = j >> 7, fp = j & 127;
    G_WS[WToff + id] = (fp < F) ? W[(long)(k * F + fp) * O + o] : 0.f;
}

__global__ __launch_bounds__(256)
void sig_k(long RUoff, const float* __restrict__ bru, long nelem)
{
    const long i = (long)blockIdx.x * 256 + threadIdx.x;
    if (i >= nelem) return;
    const float x = G_WS[RUoff + i] + bru[i & 127];
    G_WS[RUoff + i] = 1.f / (1.f + __expf(-x));
}

__global__ __launch_bounds__(256)
void gru_k(long Hoff, long PCoff, long RUoff, const float* __restrict__ bc, long nelem)
{
    const long i = (long)blockIdx.x * 256 + threadIdx.x;
    if (i >= nelem) return;
    const long row = i >> 6;
    const int col = (int)(i & 63);
    const float c = tanhf(G_WS[PCoff + i] + bc[col]);
    const float u = G_WS[RUoff + row * 128 + 64 + col];
    G_WS[Hoff + i] = u * G_WS[Hoff + i] + (1.f - u) * c;
}

__global__ __launch_bounds__(256)
void fcn_k(long H1off, const float* __restrict__ W,
           const float* __restrict__ bp, float* __restrict__ out)
{
    __shared__ float w[64];
    __shared__ float bsh;
    const int tid = threadIdx.x;
    if (tid < 64) w[tid] = W[tid];
    if (tid == 64) bsh = bp[0];
    __syncthreads();
    const long r = (long)blockIdx.x * 256 + tid;
    float acc = bsh;
#pragma unroll
    for (int i = 0; i < 64; ++i) acc += G_WS[H1off + r * 64 + i] * w[i];
    out[r] = acc;
}

extern "C" void kernel_launch(void* const* d_in, const int* in_sizes, int n_in,
                              void* d_out, int out_size, void* d_ws, size_t ws_size,
                              hipStream_t stream)
{
    (void)in_sizes; (void)n_in; (void)out_size; (void)d_ws; (void)ws_size;

    const float* adj = (const float*)d_in[0];
    const float* src = (const float*)d_in[1];
    const float* Wru[4] = {(const float*)d_in[3], (const float*)d_in[7], (const float*)d_in[11], (const float*)d_in[15]};
    const float* Bru[4] = {(const float*)d_in[4], (const float*)d_in[8], (const float*)d_in[12], (const float*)d_in[16]};
    const float* Wc[4]  = {(const float*)d_in[5], (const float*)d_in[9], (const float*)d_in[13], (const float*)d_in[17]};
    const float* Bc[4]  = {(const float*)d_in[6], (const float*)d_in[10], (const float*)d_in[14], (const float*)d_in[18]};
    const float* fcnW = (const float*)d_in[19];
    const float* fcnB = (const float*)d_in[20];
    const int Fdim[4] = {66, 128, 65, 128};
    float* out = (float*)d_out;

    const int GB = 16, NGRP = 2;

    init0_k<<<16388, 256, 0, stream>>>();

    // ---- operators: M0=S0, M1=2*S0^2-I, M2=S1, M3=2*S1^2-I ----
    rowsum_k<<<1024, 256, 0, stream>>>(adj);
    colsum_k<<<4, 256, 0, stream>>>(adj);
    ops_k<<<4096, 256, 0, stream>>>(adj);
    sgemm<true><<<dim3(16, 16, 1), 256, 0, stream>>>(
        OFF_OPS, 1024, 0, OFF_OPS, 1024, 0, OFF_OPS + 1048576L, 1024, 0, 0, 1024);
    sgemm<true><<<dim3(16, 16, 1), 256, 0, stream>>>(
        OFF_OPS + 2097152L, 1024, 0, OFF_OPS + 2097152L, 1024, 0, OFF_OPS + 3145728L, 1024, 0, 0, 1024);

    // ---- weight transforms ----
    for (int L = 0; L < 4; ++L) {
        wt2_k<<<320, 256, 0, stream>>>(Wru[L], OFF_WT2 + L * 122880L, 128, Fdim[L]);
        wt2_k<<<160, 256, 0, stream>>>(Wc[L], OFF_WT2 + L * 122880L + 81920L, 64, Fdim[L]);
    }

    // one DCGRU cell (layer L); x is external ptr or ws offset; h at Hoff (in place)
    auto cell = [&](const float* xext, long xoff, long xbs, int xd, long Hoff, int L) {
        const long wtru = OFF_WT2 + L * 122880L;
        const long wtc = wtru + 81920L;
        for (int g = 0; g < NGRP; ++g) {
            const float* xg = xext ? xext + (long)g * GB * xbs : (const float*)0;
            const long xog = (!xext && xoff >= 0) ? xoff + (long)g * GB * xbs : -1;
            const long hg = Hoff + (long)g * GB * 65536L;
            // ru = sigmoid(gconv([x|h]) Wru + bru)
            concat_f<<<GB * 512, 256, 0, stream>>>(xg, xog, xbs, xd, hg, -1, OFF_D);
            sgemm<false><<<dim3(2, 16, GB * 4), 256, 0, stream>>>(
                OFF_OPS, 1024, 1048576L, OFF_D, 640, 655360L, OFF_D + 128, 640, 655360L, 128, 1024);
            sgemm<false><<<dim3(2, GB * 16, 1), 256, 0, stream>>>(
                OFF_D, 640, 0, wtru, 128, 0, OFF_RU, 128, 0, 0, 640);
            sig_k<<<GB * 512, 256, 0, stream>>>(OFF_RU, Bru[L], (long)GB * 131072L);
            // c = tanh(gconv([x|r*h]) Wc + bc);  h = u*h + (1-u)*c
            concat_f<<<GB * 512, 256, 0, stream>>>(xg, xog, xbs, xd, hg, OFF_RU, OFF_D);
            sgemm<false><<<dim3(2, 16, GB * 4), 256, 0, stream>>>(
                OFF_OPS, 1024, 1048576L, OFF_D, 640, 655360L, OFF_D + 128, 640, 655360L, 128, 1024);
            sgemm<false><<<dim3(1, GB * 16, 1), 256, 0, stream>>>(
                OFF_D, 640, 0, wtc, 64, 0, OFF_PC, 64, 0, 0, 640);
            gru_k<<<GB * 256, 256, 0, stream>>>(hg, OFF_PC, OFF_RU, Bc[L], (long)GB * 65536L);
        }
    };

    // ---- encoder (stacked layers interleaved per timestep) ----
    for (int t = 0; t < 12; ++t) {
        cell(src + (long)t * 2048, -1, 24576, 2, OFF_H0, 0);
        cell(nullptr, OFF_H0, 65536, 64, OFF_H1, 1);
    }
    // ---- decoder (autoregressive, go token = zeros) ----
    for (int t = 0; t < 12; ++t) {
        const float* xp = t ? out + (long)(t - 1) * 32768 : (const float*)0;
        cell(xp, -1, 1024, 1, OFF_H0, 2);
        cell(nullptr, OFF_H0, 65536, 64, OFF_H1, 3);
        fcn_k<<<128, 256, 0, stream>>>(OFF_H1, fcnW, fcnB, out + (long)t * 32768);
    }
}

// Round 8
// 13124.634 us; speedup vs baseline: 3.6925x; 3.6925x over previous
//
#include <hip/hip_runtime.h>

typedef unsigned short u16;
typedef __attribute__((ext_vector_type(4))) float f32x4;
typedef _Float16 f16x8 __attribute__((ext_vector_type(8)));
typedef __attribute__((ext_vector_type(8))) short short8;

// Static device workspace: 40,339,456 f32 = 161.4 MB. Module-owned; every
// region written before read on every call.
#define OFF_OPS   0L          // [4][1024][1024] f32: S0, 2S0^2-I, S1, 2S1^2-I
#define OFF_WT2   4194304L    // 4 x ([640][128] Wru | [640][64] Wc) f32
#define OFF_H0    4685824L    // [32*1024][64] f32
#define OFF_H1    6782976L    // [32*1024][64] f32
#define OFF_RSUM  8880128L    // [1024]
#define OFF_CSUM  8881152L    // [1024]
#define OFF_D     8882176L    // [32][1024][640] f32
#define OFF_RU    29853696L   // [32*1024][128] f32
#define OFF_PC    34048000L   // [32*1024][64] f32
#define OFF_OPSH  36145152L   // u16 region: [4][1024][1024] f16
#define OFF_XTH   38242304L   // u16 region: [32][128][1024] f16
#define WS_TOTAL  40339456L

__device__ static float G_WS[WS_TOTAL];

__device__ __forceinline__ u16 f2h(float f) {
    return __builtin_bit_cast(u16, (_Float16)f);
}

__device__ __forceinline__ void gload_lds16(const void* g, void* l) {
    __builtin_amdgcn_global_load_lds((__attribute__((address_space(1))) void*)g,
                                     (__attribute__((address_space(3))) void*)l,
                                     16, 0, 0);
}

// zero H0,H1 (contiguous 4,194,304) and csum (1024)
__global__ __launch_bounds__(256)
void init0_k()
{
    const long i = (long)blockIdx.x * 256 + threadIdx.x;
    if (i < 4194304L) G_WS[OFF_H0 + i] = 0.f;
    else if (i < 4195328L) G_WS[OFF_CSUM + (i - 4194304L)] = 0.f;
}

// ---------------- f32 vector GEMM (projection + P2 setup; green anchor) ----
// C[M,N] = A[M,K] @ B[K,N]; z=(bz<<2)|mat.
template<bool P2F>
__global__ __launch_bounds__(256)
void sgemm(long Aoff, int lda, long sAm,
           long Boff, int ldb, long sBb,
           long Coff, int ldc, long sCb, long sCm,
           int K)
{
    __shared__ __attribute__((aligned(16))) float As[16][68];
    __shared__ __attribute__((aligned(16))) float Bs[16][68];
    const int tid = threadIdx.x;
    const int tm = tid & 15, tn = tid >> 4;
    const int m0 = blockIdx.y * 64, n0 = blockIdx.x * 64;
    const int z = blockIdx.z;
    const int mat = z & 3;
    const long bz = z >> 2;
    const float* A = G_WS + Aoff + (long)mat * sAm;
    const float* B = G_WS + Boff + bz * sBb;

    float acc[4][4] = {};
    const int arow = tid >> 2, akq = (tid & 3) * 4;
    const int brow = tid >> 4, bn4 = (tid & 15) * 4;

    for (int kt = 0; kt < K; kt += 16) {
        __syncthreads();
#pragma unroll
        for (int i = 0; i < 4; ++i)
            As[akq + i][arow] = A[(long)(m0 + arow) * lda + kt + akq + i];
#pragma unroll
        for (int i = 0; i < 4; ++i)
            Bs[brow][bn4 + i] = B[(long)(kt + brow) * ldb + n0 + bn4 + i];
        __syncthreads();
#pragma unroll
        for (int kk = 0; kk < 16; ++kk) {
            const f32x4 av = *(const f32x4*)&As[kk][tm * 4];
            const f32x4 bv = *(const f32x4*)&Bs[kk][tn * 4];
#pragma unroll
            for (int i = 0; i < 4; ++i)
#pragma unroll
                for (int j = 0; j < 4; ++j)
                    acc[i][j] += av[i] * bv[j];
        }
    }

    float* C = G_WS + Coff + bz * sCb + (long)mat * sCm;
#pragma unroll
    for (int i = 0; i < 4; ++i)
#pragma unroll
        for (int j = 0; j < 4; ++j) {
            const int r = m0 + tm * 4 + i, c = n0 + tn * 4 + j;
            float v = acc[i][j];
            if (P2F) v = 2.f * v - (r == c ? 1.f : 0.f);
            C[(long)r * ldc + c] = v;
        }
}

// ---------------- f16 MFMA diffusion GEMM ----------------------------------
// For z=(b<<2)|mat: D[b][m][128+mat*128+f] = sum_k OPSH[mat][m][k]*XTH[b][f][k]
// 128x128 tile (y: 8), BK=64, 4 waves each 64x64. m97-pattern staging.
__global__ __launch_bounds__(256)
void dmfma_k()
{
    __shared__ __attribute__((aligned(16))) u16 lds[2 * 128 * 64];
    u16* ldsA = lds;
    u16* ldsB = lds + 128 * 64;
    const u16* OPSH = (const u16*)(G_WS + OFF_OPSH);
    const u16* XTH  = (const u16*)(G_WS + OFF_XTH);

    const int tid = threadIdx.x, lane = tid & 63, wv = tid >> 6;
    const int lrow = lane & 15, lkq = lane >> 4;
    const int m0 = blockIdx.y * 128;
    const int z = blockIdx.z;
    const int mat = z & 3, b = z >> 2;
    const u16* A  = OPSH + (long)mat * 1048576L;
    const u16* Bt = XTH + (long)b * 131072L;
    const int wm = (wv >> 1) * 64, wn = (wv & 1) * 64;

    f32x4 acc[4][4];
#pragma unroll
    for (int i = 0; i < 4; ++i)
#pragma unroll
        for (int j = 0; j < 4; ++j)
            acc[i][j] = f32x4{0.f, 0.f, 0.f, 0.f};

    for (int kt = 0; kt < 1024; kt += 64) {
        __syncthreads();
#pragma unroll
        for (int i = 0; i < 4; ++i) {
            const int ib = i * 4 + wv;                 // 0..15
            const int row = ib * 8 + (lane >> 3);
            const int c8 = lane & 7;
            gload_lds16(A + (long)(m0 + row) * 1024 + kt + c8 * 8, ldsA + ib * 512);
            gload_lds16(Bt + (long)row * 1024 + kt + c8 * 8, ldsB + ib * 512);
        }
        asm volatile("s_waitcnt vmcnt(0)" ::: "memory");
        __syncthreads();

#pragma unroll
        for (int kk = 0; kk < 2; ++kk) {
            f16x8 af[4];
#pragma unroll
            for (int mf = 0; mf < 4; ++mf)
                af[mf] = *(const f16x8*)(ldsA + (wm + mf * 16 + lrow) * 64 + kk * 32 + lkq * 8);
#pragma unroll
            for (int nf = 0; nf < 4; ++nf) {
                f16x8 bfv = *(const f16x8*)(ldsB + (wn + nf * 16 + lrow) * 64 + kk * 32 + lkq * 8);
#pragma unroll
                for (int mf = 0; mf < 4; ++mf)
                    acc[mf][nf] = __builtin_amdgcn_mfma_f32_16x16x32_f16(af[mf], bfv, acc[mf][nf], 0, 0, 0);
            }
        }
    }

    float* Dp = G_WS + OFF_D + ((long)b * 1024 + m0) * 640 + 128 + mat * 128;
#pragma unroll
    for (int mf = 0; mf < 4; ++mf)
#pragma unroll
        for (int nf = 0; nf < 4; ++nf)
#pragma unroll
            for (int j = 0; j < 4; ++j)
                Dp[(long)(wm + mf * 16 + lkq * 4 + j) * 640 + wn + nf * 16 + lrow] = acc[mf][nf][j];
}

// D[b][n][0:128] f32 -> XTH[b][f][n] f16 (transposed, K-contiguous for MFMA B^T)
__global__ __launch_bounds__(256)
void tr_k()
{
    const int nt = blockIdx.x, b = blockIdx.y;
    const int n0 = nt * 64;
    __shared__ u16 t[64][136];
    const int tid = threadIdx.x;
    {
        const int nl = tid >> 2;
        const int cg = (tid & 3) * 32;
        const float* drow = G_WS + OFF_D + ((long)b * 1024 + n0 + nl) * 640;
#pragma unroll
        for (int i = 0; i < 32; ++i) t[nl][cg + i] = f2h(drow[cg + i]);
    }
    __syncthreads();
    {
        const int f = tid >> 1;
        const int nh = (tid & 1) * 32;
        alignas(16) u16 ov[32];
#pragma unroll
        for (int i = 0; i < 32; ++i) ov[i] = t[nh + i][f];
        u16* xt = (u16*)(G_WS + OFF_XTH) + ((long)b * 128 + f) * 1024 + n0 + nh;
#pragma unroll
        for (int i = 0; i < 32; i += 8) *(short8*)(xt + i) = *(const short8*)(ov + i);
    }
}

// OPS f32 -> OPSH f16
__global__ __launch_bounds__(256)
void opsh_k()
{
    const long i = (long)blockIdx.x * 256 + threadIdx.x;   // 16384 blocks
    ((u16*)(G_WS + OFF_OPSH))[i] = f2h(G_WS[OFF_OPS + i]);
}

// D[gr][f] (row 640, k0 block) = [x | (r?)*h | zero-pad], f in [0,128)
__global__ __launch_bounds__(256)
void concat_f(const float* __restrict__ xext, long xoff, long xbs, int xd,
              long Hoff, long RUoff)
{
    const long idx = (long)blockIdx.x * 256 + threadIdx.x;
    const int f = (int)(idx & 127);
    const long gr = idx >> 7;
    const long bl = gr >> 10, n = gr & 1023;
    const float* x = xext ? xext : (xoff >= 0 ? G_WS + xoff : (const float*)0);
    float v = 0.f;
    if (f < xd) {
        if (x) v = x[bl * xbs + n * xd + f];
    } else if (f < xd + 64) {
        v = G_WS[Hoff + gr * 64 + (f - xd)];
        if (RUoff >= 0) v *= G_WS[RUoff + gr * 128 + (f - xd)];
    }
    G_WS[OFF_D + gr * 640 + f] = v;
}

__global__ __launch_bounds__(256)
void rowsum_k(const float* __restrict__ adj)
{
    const int r = blockIdx.x, tid = threadIdx.x;
    float s = 0.f;
    for (int c = tid; c < 1024; c += 256) s += adj[(long)r * 1024 + c];
#pragma unroll
    for (int o = 32; o; o >>= 1) s += __shfl_down(s, o, 64);
    __shared__ float ps[4];
    if ((tid & 63) == 0) ps[tid >> 6] = s;
    __syncthreads();
    if (tid == 0) G_WS[OFF_RSUM + r] = ps[0] + ps[1] + ps[2] + ps[3];
}

__global__ __launch_bounds__(256)
void colsum_k(const float* __restrict__ adj)
{
    const int c = blockIdx.x * 256 + threadIdx.x;
    float s = 0.f;
    for (int r = 0; r < 1024; ++r) s += adj[(long)r * 1024 + c];
    G_WS[OFF_CSUM + c] = s;
}

// OPS[0][m][n]=adj[n][m]/rsum[n]  OPS[2][m][n]=adj[m][n]/csum[n]
__global__ __launch_bounds__(256)
void ops_k(const float* __restrict__ adj)
{
    const int id = blockIdx.x * 256 + threadIdx.x;
    const int m = id >> 10, n = id & 1023;
    G_WS[OFF_OPS + id] = adj[(long)n * 1024 + m] / fmaxf(G_WS[OFF_RSUM + n], 1e-8f);
    G_WS[OFF_OPS + 2 * 1048576L + id] = adj[id] / fmaxf(G_WS[OFF_CSUM + n], 1e-8f);
}

// WT[j][o] ([640][O]) = (fp<F) ? W[(k*F+fp)*O + o] : 0, j=k*128+fp
__global__ __launch_bounds__(256)
void wt2_k(const float* __restrict__ W, long WToff, int O, int F)
{
    const int id = blockIdx.x * 256 + threadIdx.x;
    if (id >= 640 * O) return;
    const int j = id / O, o = id % O;
    const int k = j >> 7, fp = j & 127;
    G_WS[WToff + id] = (fp < F) ? W[(long)(k * F + fp) * O + o] : 0.f;
}

__global__ __launch_bounds__(256)
void sig_k(const float* __restrict__ bru, long nelem)
{
    const long i = (long)blockIdx.x * 256 + threadIdx.x;
    if (i >= nelem) return;
    const float x = G_WS[OFF_RU + i] + bru[i & 127];
    G_WS[OFF_RU + i] = 1.f / (1.f + __expf(-x));
}

__global__ __launch_bounds__(256)
void gru_k(long Hoff, const float* __restrict__ bc, long nelem)
{
    const long i = (long)blockIdx.x * 256 + threadIdx.x;
    if (i >= nelem) return;
    const long row = i >> 6;
    const int col = (int)(i & 63);
    const float c = tanhf(G_WS[OFF_PC + i] + bc[col]);
    const float u = G_WS[OFF_RU + row * 128 + 64 + col];
    G_WS[Hoff + i] = u * G_WS[Hoff + i] + (1.f - u) * c;
}

__global__ __launch_bounds__(256)
void fcn_k(const float* __restrict__ W, const float* __restrict__ bp,
           float* __restrict__ out)
{
    __shared__ float w[64];
    __shared__ float bsh;
    const int tid = threadIdx.x;
    if (tid < 64) w[tid] = W[tid];
    if (tid == 64) bsh = bp[0];
    __syncthreads();
    const long r = (long)blockIdx.x * 256 + tid;
    float acc = bsh;
#pragma unroll
    for (int i = 0; i < 64; ++i) acc += G_WS[OFF_H1 + r * 64 + i] * w[i];
    out[r] = acc;
}

extern "C" void kernel_launch(void* const* d_in, const int* in_sizes, int n_in,
                              void* d_out, int out_size, void* d_ws, size_t ws_size,
                              hipStream_t stream)
{
    (void)in_sizes; (void)n_in; (void)out_size; (void)d_ws; (void)ws_size;

    const float* adj = (const float*)d_in[0];
    const float* src = (const float*)d_in[1];
    const float* Wru[4] = {(const float*)d_in[3], (const float*)d_in[7], (const float*)d_in[11], (const float*)d_in[15]};
    const float* Bru[4] = {(const float*)d_in[4], (const float*)d_in[8], (const float*)d_in[12], (const float*)d_in[16]};
    const float* Wc[4]  = {(const float*)d_in[5], (const float*)d_in[9], (const float*)d_in[13], (const float*)d_in[17]};
    const float* Bc[4]  = {(const float*)d_in[6], (const float*)d_in[10], (const float*)d_in[14], (const float*)d_in[18]};
    const float* fcnW = (const float*)d_in[19];
    const float* fcnB = (const float*)d_in[20];
    const int Fdim[4] = {66, 128, 65, 128};
    float* out = (float*)d_out;

    init0_k<<<16388, 256, 0, stream>>>();

    // ---- operators: M0=S0, M1=2*S0^2-I, M2=S1, M3=2*S1^2-I (f32) + f16 copy
    rowsum_k<<<1024, 256, 0, stream>>>(adj);
    colsum_k<<<4, 256, 0, stream>>>(adj);
    ops_k<<<4096, 256, 0, stream>>>(adj);
    sgemm<true><<<dim3(16, 16, 1), 256, 0, stream>>>(
        OFF_OPS, 1024, 0, OFF_OPS, 1024, 0, OFF_OPS + 1048576L, 1024, 0, 0, 1024);
    sgemm<true><<<dim3(16, 16, 1), 256, 0, stream>>>(
        OFF_OPS + 2097152L, 1024, 0, OFF_OPS + 2097152L, 1024, 0, OFF_OPS + 3145728L, 1024, 0, 0, 1024);
    opsh_k<<<16384, 256, 0, stream>>>();

    // ---- weight transforms ----
    for (int L = 0; L < 4; ++L) {
        wt2_k<<<320, 256, 0, stream>>>(Wru[L], OFF_WT2 + L * 122880L, 128, Fdim[L]);
        wt2_k<<<160, 256, 0, stream>>>(Wc[L], OFF_WT2 + L * 122880L + 81920L, 64, Fdim[L]);
    }

    // one DCGRU cell (layer L), full batch (32); h at Hoff updated in place
    auto cell = [&](const float* xext, long xoff, long xbs, int xd, long Hoff, int L) {
        const long wtru = OFF_WT2 + L * 122880L;
        const long wtc = wtru + 81920L;
        // ru = sigmoid(gconv([x|h]) Wru + bru)
        concat_f<<<16384, 256, 0, stream>>>(xext, xoff, xbs, xd, Hoff, -1);
        tr_k<<<dim3(16, 32), 256, 0, stream>>>();
        dmfma_k<<<dim3(1, 8, 128), 256, 0, stream>>>();
        sgemm<false><<<dim3(2, 512, 1), 256, 0, stream>>>(
            OFF_D, 640, 0, wtru, 128, 0, OFF_RU, 128, 0, 0, 640);
        sig_k<<<16384, 256, 0, stream>>>(Bru[L], 4194304L);
        // c = tanh(gconv([x|r*h]) Wc + bc);  h = u*h + (1-u)*c
        concat_f<<<16384, 256, 0, stream>>>(xext, xoff, xbs, xd, Hoff, OFF_RU);
        tr_k<<<dim3(16, 32), 256, 0, stream>>>();
        dmfma_k<<<dim3(1, 8, 128), 256, 0, stream>>>();
        sgemm<false><<<dim3(1, 512, 1), 256, 0, stream>>>(
            OFF_D, 640, 0, wtc, 64, 0, OFF_PC, 64, 0, 0, 640);
        gru_k<<<8192, 256, 0, stream>>>(Hoff, Bc[L], 2097152L);
    };

    // ---- encoder (stacked layers interleaved per timestep) ----
    for (int t = 0; t < 12; ++t) {
        cell(src + (long)t * 2048, -1, 24576, 2, OFF_H0, 0);
        cell(nullptr, OFF_H0, 65536, 64, OFF_H1, 1);
    }
    // ---- decoder (autoregressive, go token = zeros) ----
    for (int t = 0; t < 12; ++t) {
        const float* xp = t ? out + (long)(t - 1) * 32768 : (const float*)0;
        cell(xp, -1, 1024, 1, OFF_H0, 2);
        cell(nullptr, OFF_H0, 65536, 64, OFF_H1, 3);
        fcn_k<<<128, 256, 0, stream>>>(fcnW, fcnB, out + (long)t * 32768);
    }
}

// Round 9
// 10846.098 us; speedup vs baseline: 4.4682x; 1.2101x over previous
//
#include <hip/hip_runtime.h>

typedef unsigned short u16;
typedef __attribute__((ext_vector_type(4))) float f32x4;
typedef _Float16 f16x8 __attribute__((ext_vector_type(8)));
typedef __attribute__((ext_vector_type(8))) short short8;

// Static device workspace: 27,510,784 f32 = 110 MB. Module-owned; every
// region written before read on every call.
#define OFF_OPS   0L          // [4][1024][1024] f32: S0, 2S0^2-I, S1, 2S1^2-I
#define OFF_H0    4194304L    // [32*1024][64] f32
#define OFF_H1    6291456L    // [32*1024][64] f32
#define OFF_RSUM  8388608L    // [1024] f32
#define OFF_CSUM  8389632L    // [1024] f32
#define OFF_RU    8390656L    // [32*1024][128] f32
#define OFF_DH    12584960L   // u16 region: [32][1024][640] f16
#define OFF_OPSH  23070720L   // u16 region: [4][1024][1024] f16
#define OFF_XTH   25167872L   // u16 region: [32][128][1024] f16
#define OFF_WTH   27265024L   // u16 region: 4 x ([128][640] Wru^T | [64][640] Wc^T) f16
#define WS_TOTAL  27510784L

__device__ static float G_WS[WS_TOTAL];

__device__ __forceinline__ u16 f2h(float f) {
    return __builtin_bit_cast(u16, (_Float16)f);
}

__device__ __forceinline__ void gload_lds16(const void* g, void* l) {
    __builtin_amdgcn_global_load_lds((__attribute__((address_space(1))) void*)g,
                                     (__attribute__((address_space(3))) void*)l,
                                     16, 0, 0);
}

// zero H0,H1 (contiguous 4,194,304 from OFF_H0) and csum (1024)
__global__ __launch_bounds__(256)
void init0_k()
{
    const long i = (long)blockIdx.x * 256 + threadIdx.x;
    if (i < 4194304L) G_WS[OFF_H0 + i] = 0.f;
    else if (i < 4195328L) G_WS[OFF_CSUM + (i - 4194304L)] = 0.f;
}

// ---------------- f32 vector GEMM (P2 operator setup only, 2 dispatches) ---
template<bool P2F>
__global__ __launch_bounds__(256)
void sgemm(long Aoff, int lda, long Boff, int ldb, long Coff, int ldc, int K)
{
    __shared__ __attribute__((aligned(16))) float As[16][68];
    __shared__ __attribute__((aligned(16))) float Bs[16][68];
    const int tid = threadIdx.x;
    const int tm = tid & 15, tn = tid >> 4;
    const int m0 = blockIdx.y * 64, n0 = blockIdx.x * 64;
    const float* A = G_WS + Aoff;
    const float* B = G_WS + Boff;

    float acc[4][4] = {};
    const int arow = tid >> 2, akq = (tid & 3) * 4;
    const int brow = tid >> 4, bn4 = (tid & 15) * 4;

    for (int kt = 0; kt < K; kt += 16) {
        __syncthreads();
#pragma unroll
        for (int i = 0; i < 4; ++i)
            As[akq + i][arow] = A[(long)(m0 + arow) * lda + kt + akq + i];
#pragma unroll
        for (int i = 0; i < 4; ++i)
            Bs[brow][bn4 + i] = B[(long)(kt + brow) * ldb + n0 + bn4 + i];
        __syncthreads();
#pragma unroll
        for (int kk = 0; kk < 16; ++kk) {
            const f32x4 av = *(const f32x4*)&As[kk][tm * 4];
            const f32x4 bv = *(const f32x4*)&Bs[kk][tn * 4];
#pragma unroll
            for (int i = 0; i < 4; ++i)
#pragma unroll
                for (int j = 0; j < 4; ++j)
                    acc[i][j] += av[i] * bv[j];
        }
    }

    float* C = G_WS + Coff;
#pragma unroll
    for (int i = 0; i < 4; ++i)
#pragma unroll
        for (int j = 0; j < 4; ++j) {
            const int r = m0 + tm * 4 + i, c = n0 + tn * 4 + j;
            float v = acc[i][j];
            if (P2F) v = 2.f * v - (r == c ? 1.f : 0.f);
            C[(long)r * ldc + c] = v;
        }
}

// ---------------- f16 MFMA diffusion GEMM ----------------------------------
// z=(b<<2)|mat: DH[b][m][128+mat*128+f] = sum_k OPSH[mat][m][k]*XTH[b][f][k]
// 128x128 tile (y: 8), BK=64, 4 waves each 64x64.
__global__ __launch_bounds__(256)
void dmfma_k()
{
    __shared__ __attribute__((aligned(16))) u16 lds[2 * 128 * 64];
    u16* ldsA = lds;
    u16* ldsB = lds + 128 * 64;
    const u16* OPSH = (const u16*)(G_WS + OFF_OPSH);
    const u16* XTH  = (const u16*)(G_WS + OFF_XTH);

    const int tid = threadIdx.x, lane = tid & 63, wv = tid >> 6;
    const int lrow = lane & 15, lkq = lane >> 4;
    const int m0 = blockIdx.y * 128;
    const int z = blockIdx.z;
    const int mat = z & 3, b = z >> 2;
    const u16* A  = OPSH + (long)mat * 1048576L;
    const u16* Bt = XTH + (long)b * 131072L;
    const int wm = (wv >> 1) * 64, wn = (wv & 1) * 64;

    f32x4 acc[4][4];
#pragma unroll
    for (int i = 0; i < 4; ++i)
#pragma unroll
        for (int j = 0; j < 4; ++j)
            acc[i][j] = f32x4{0.f, 0.f, 0.f, 0.f};

    for (int kt = 0; kt < 1024; kt += 64) {
        __syncthreads();
#pragma unroll
        for (int i = 0; i < 4; ++i) {
            const int ib = i * 4 + wv;                 // 0..15
            const int row = ib * 8 + (lane >> 3);
            const int c8 = lane & 7;
            gload_lds16(A + (long)(m0 + row) * 1024 + kt + c8 * 8, ldsA + ib * 512);
            gload_lds16(Bt + (long)row * 1024 + kt + c8 * 8, ldsB + ib * 512);
        }
        asm volatile("s_waitcnt vmcnt(0)" ::: "memory");
        __syncthreads();

#pragma unroll
        for (int kk = 0; kk < 2; ++kk) {
            f16x8 af[4];
#pragma unroll
            for (int mf = 0; mf < 4; ++mf)
                af[mf] = *(const f16x8*)(ldsA + (wm + mf * 16 + lrow) * 64 + kk * 32 + lkq * 8);
#pragma unroll
            for (int nf = 0; nf < 4; ++nf) {
                f16x8 bfv = *(const f16x8*)(ldsB + (wn + nf * 16 + lrow) * 64 + kk * 32 + lkq * 8);
#pragma unroll
                for (int mf = 0; mf < 4; ++mf)
                    acc[mf][nf] = __builtin_amdgcn_mfma_f32_16x16x32_f16(af[mf], bfv, acc[mf][nf], 0, 0, 0);
            }
        }
    }

    u16* Dp = (u16*)(G_WS + OFF_DH) + ((long)b * 1024 + m0) * 640 + 128 + mat * 128;
#pragma unroll
    for (int mf = 0; mf < 4; ++mf)
#pragma unroll
        for (int nf = 0; nf < 4; ++nf)
#pragma unroll
            for (int j = 0; j < 4; ++j)
                Dp[(long)(wm + mf * 16 + lkq * 4 + j) * 640 + wn + nf * 16 + lrow] =
                    f2h(acc[mf][nf][j]);
}

// ---------------- f16 MFMA projection with fused epilogue -------------------
// A = DH [32768][640], B^T = WTH[...] [N][640]. Grid y: 256 (128-row tiles).
// EPI 0: RU[gr][col] = sigmoid(acc + bias[col])           (N=128)
// EPI 1: c=tanh(acc+bias); u=RU[gr][64+col]; H[gr][col]=u*H+(1-u)*c  (N=64)
template<int BN, int EPI>
__global__ __launch_bounds__(256)
void pgemm(long WThoff, const float* __restrict__ bias, long Hoff)
{
    constexpr int NF = BN / 32;
    __shared__ __attribute__((aligned(16))) u16 lds[128 * 64 + BN * 64];
    u16* ldsA = lds;
    u16* ldsB = lds + 128 * 64;
    const u16* A  = (const u16*)(G_WS + OFF_DH);
    const u16* Bt = (const u16*)(G_WS + WThoff);

    const int tid = threadIdx.x, lane = tid & 63, wv = tid >> 6;
    const int lrow = lane & 15, lkq = lane >> 4;
    const int m0 = blockIdx.y * 128;
    const int wm = (wv >> 1) * 64, wn = (wv & 1) * (BN / 2);

    f32x4 acc[4][NF];
#pragma unroll
    for (int i = 0; i < 4; ++i)
#pragma unroll
        for (int j = 0; j < NF; ++j)
            acc[i][j] = f32x4{0.f, 0.f, 0.f, 0.f};

    for (int kt = 0; kt < 640; kt += 64) {
        __syncthreads();
#pragma unroll
        for (int i = 0; i < 4; ++i) {
            const int ib = i * 4 + wv;
            const int row = ib * 8 + (lane >> 3);
            const int c8 = lane & 7;
            gload_lds16(A + (long)(m0 + row) * 640 + kt + c8 * 8, ldsA + ib * 512);
        }
#pragma unroll
        for (int i = 0; i < BN / 32; ++i) {
            const int ib = i * 4 + wv;
            const int row = ib * 8 + (lane >> 3);
            const int c8 = lane & 7;
            gload_lds16(Bt + (long)row * 640 + kt + c8 * 8, ldsB + ib * 512);
        }
        asm volatile("s_waitcnt vmcnt(0)" ::: "memory");
        __syncthreads();

#pragma unroll
        for (int kk = 0; kk < 2; ++kk) {
            f16x8 af[4];
#pragma unroll
            for (int mf = 0; mf < 4; ++mf)
                af[mf] = *(const f16x8*)(ldsA + (wm + mf * 16 + lrow) * 64 + kk * 32 + lkq * 8);
#pragma unroll
            for (int nf = 0; nf < NF; ++nf) {
                f16x8 bfv = *(const f16x8*)(ldsB + (wn + nf * 16 + lrow) * 64 + kk * 32 + lkq * 8);
#pragma unroll
                for (int mf = 0; mf < 4; ++mf)
                    acc[mf][nf] = __builtin_amdgcn_mfma_f32_16x16x32_f16(af[mf], bfv, acc[mf][nf], 0, 0, 0);
            }
        }
    }

#pragma unroll
    for (int mf = 0; mf < 4; ++mf)
#pragma unroll
        for (int nf = 0; nf < NF; ++nf)
#pragma unroll
            for (int j = 0; j < 4; ++j) {
                const long gr = m0 + wm + mf * 16 + lkq * 4 + j;
                const int col = wn + nf * 16 + lrow;
                const float v = acc[mf][nf][j] + bias[col];
                if (EPI == 0) {
                    G_WS[OFF_RU + gr * 128 + col] = 1.f / (1.f + __expf(-v));
                } else {
                    const float c = tanhf(v);
                    const float u = G_WS[OFF_RU + gr * 128 + 64 + col];
                    float* hp = G_WS + Hoff + gr * 64 + col;
                    *hp = u * *hp + (1.f - u) * c;
                }
            }
}

// ---------------- fused concat + transpose ----------------------------------
// DH[b][n][0:128] = [x | (r?)*h | 0-pad] (f16) and XTH[b][f][n] (f16).
__global__ __launch_bounds__(256)
void concat_T(const float* __restrict__ xext, long xoff, long xbs, int xd,
              long Hoff, long RUoff)
{
    const int nt = blockIdx.x, b = blockIdx.y;
    const int n0 = nt * 64;
    __shared__ u16 t[64][136];
    const int tid = threadIdx.x;
    const float* x = xext ? xext : (xoff >= 0 ? G_WS + xoff : (const float*)0);
    {
        const int nl = tid >> 2;
        const int cg = (tid & 3) * 32;
        const long gr = (long)b * 1024 + n0 + nl;
        const float* hrow = G_WS + Hoff + gr * 64;
        const float* rrow = (RUoff >= 0) ? G_WS + RUoff + gr * 128 : (const float*)0;
        const float* xrow = x ? x + (long)b * xbs + (long)(n0 + nl) * xd : (const float*)0;
        alignas(16) u16 vals[32];
#pragma unroll
        for (int i = 0; i < 32; ++i) {
            const int f = cg + i;
            float v = 0.f;
            if (f < xd) { if (xrow) v = xrow[f]; }
            else if (f < xd + 64) {
                const int ff = f - xd;
                v = hrow[ff];
                if (rrow) v *= rrow[ff];
            }
            vals[i] = f2h(v);
        }
        u16* grow = (u16*)(G_WS + OFF_DH) + gr * 640 + cg;
#pragma unroll
        for (int i = 0; i < 32; i += 8) *(short8*)(grow + i) = *(const short8*)(vals + i);
#pragma unroll
        for (int i = 0; i < 32; ++i) t[nl][cg + i] = vals[i];
    }
    __syncthreads();
    {
        const int f = tid >> 1;
        const int nh = (tid & 1) * 32;
        alignas(16) u16 ov[32];
#pragma unroll
        for (int i = 0; i < 32; ++i) ov[i] = t[nh + i][f];
        u16* xt = (u16*)(G_WS + OFF_XTH) + ((long)b * 128 + f) * 1024 + n0 + nh;
#pragma unroll
        for (int i = 0; i < 32; i += 8) *(short8*)(xt + i) = *(const short8*)(ov + i);
    }
}

__global__ __launch_bounds__(256)
void rowsum_k(const float* __restrict__ adj)
{
    const int r = blockIdx.x, tid = threadIdx.x;
    float s = 0.f;
    for (int c = tid; c < 1024; c += 256) s += adj[(long)r * 1024 + c];
#pragma unroll
    for (int o = 32; o; o >>= 1) s += __shfl_down(s, o, 64);
    __shared__ float ps[4];
    if ((tid & 63) == 0) ps[tid >> 6] = s;
    __syncthreads();
    if (tid == 0) G_WS[OFF_RSUM + r] = ps[0] + ps[1] + ps[2] + ps[3];
}

__global__ __launch_bounds__(256)
void colsum_k(const float* __restrict__ adj)
{
    const int c = blockIdx.x * 256 + threadIdx.x;
    float s = 0.f;
    for (int r = 0; r < 1024; ++r) s += adj[(long)r * 1024 + c];
    G_WS[OFF_CSUM + c] = s;
}

// OPS[0][m][n]=adj[n][m]/rsum[n]  OPS[2][m][n]=adj[m][n]/csum[n]
__global__ __launch_bounds__(256)
void ops_k(const float* __restrict__ adj)
{
    const int id = blockIdx.x * 256 + threadIdx.x;
    const int m = id >> 10, n = id & 1023;
    G_WS[OFF_OPS + id] = adj[(long)n * 1024 + m] / fmaxf(G_WS[OFF_RSUM + n], 1e-8f);
    G_WS[OFF_OPS + 2 * 1048576L + id] = adj[id] / fmaxf(G_WS[OFF_CSUM + n], 1e-8f);
}

// OPS f32 -> OPSH f16
__global__ __launch_bounds__(256)
void opsh_k()
{
    const long i = (long)blockIdx.x * 256 + threadIdx.x;   // 16384 blocks
    ((u16*)(G_WS + OFF_OPSH))[i] = f2h(G_WS[OFF_OPS + i]);
}

// WTH[o][j] ([O][640] f16, K-contiguous) = (fp<F) ? W[(k*F+fp)*O+o] : 0, j=k*128+fp
__global__ __launch_bounds__(256)
void wth_k(const float* __restrict__ W, long WThoff, int O, int F)
{
    const int id = blockIdx.x * 256 + threadIdx.x;
    if (id >= O * 640) return;
    const int o = id / 640, j = id % 640;
    const int k = j >> 7, fp = j & 127;
    ((u16*)(G_WS + WThoff))[id] = (fp < F) ? f2h(W[(long)(k * F + fp) * O + o]) : (u16)0;
}

__global__ __launch_bounds__(256)
void fcn_k(const float* __restrict__ W, const float* __restrict__ bp,
           float* __restrict__ out)
{
    __shared__ float w[64];
    __shared__ float bsh;
    const int tid = threadIdx.x;
    if (tid < 64) w[tid] = W[tid];
    if (tid == 64) bsh = bp[0];
    __syncthreads();
    const long r = (long)blockIdx.x * 256 + tid;
    float acc = bsh;
#pragma unroll
    for (int i = 0; i < 64; ++i) acc += G_WS[OFF_H1 + r * 64 + i] * w[i];
    out[r] = acc;
}

extern "C" void kernel_launch(void* const* d_in, const int* in_sizes, int n_in,
                              void* d_out, int out_size, void* d_ws, size_t ws_size,
                              hipStream_t stream)
{
    (void)in_sizes; (void)n_in; (void)out_size; (void)d_ws; (void)ws_size;

    const float* adj = (const float*)d_in[0];
    const float* src = (const float*)d_in[1];
    const float* Wru[4] = {(const float*)d_in[3], (const float*)d_in[7], (const float*)d_in[11], (const float*)d_in[15]};
    const float* Bru[4] = {(const float*)d_in[4], (const float*)d_in[8], (const float*)d_in[12], (const float*)d_in[16]};
    const float* Wc[4]  = {(const float*)d_in[5], (const float*)d_in[9], (const float*)d_in[13], (const float*)d_in[17]};
    const float* Bc[4]  = {(const float*)d_in[6], (const float*)d_in[10], (const float*)d_in[14], (const float*)d_in[18]};
    const float* fcnW = (const float*)d_in[19];
    const float* fcnB = (const float*)d_in[20];
    const int Fdim[4] = {66, 128, 65, 128};
    float* out = (float*)d_out;

    init0_k<<<16388, 256, 0, stream>>>();

    // ---- operators: M0=S0, M1=2*S0^2-I, M2=S1, M3=2*S1^2-I (f32) + f16 copy
    rowsum_k<<<1024, 256, 0, stream>>>(adj);
    colsum_k<<<4, 256, 0, stream>>>(adj);
    ops_k<<<4096, 256, 0, stream>>>(adj);
    sgemm<true><<<dim3(16, 16), 256, 0, stream>>>(
        OFF_OPS, 1024, OFF_OPS, 1024, OFF_OPS + 1048576L, 1024, 1024);
    sgemm<true><<<dim3(16, 16), 256, 0, stream>>>(
        OFF_OPS + 2097152L, 1024, OFF_OPS + 2097152L, 1024, OFF_OPS + 3145728L, 1024, 1024);
    opsh_k<<<16384, 256, 0, stream>>>();

    // ---- weight transforms (f16, K-contiguous [O][640]) ----
    for (int L = 0; L < 4; ++L) {
        wth_k<<<320, 256, 0, stream>>>(Wru[L], OFF_WTH + L * 61440L, 128, Fdim[L]);
        wth_k<<<160, 256, 0, stream>>>(Wc[L],  OFF_WTH + L * 61440L + 40960L, 64, Fdim[L]);
    }

    // one DCGRU cell (layer L), full batch (32); h at Hoff updated in place
    auto cell = [&](const float* xext, long xoff, long xbs, int xd, long Hoff, int L) {
        const long wtru = OFF_WTH + L * 61440L;
        const long wtc = wtru + 40960L;
        // ru = sigmoid(gconv([x|h]) Wru + bru)
        concat_T<<<dim3(16, 32), 256, 0, stream>>>(xext, xoff, xbs, xd, Hoff, -1);
        dmfma_k<<<dim3(1, 8, 128), 256, 0, stream>>>();
        pgemm<128, 0><<<dim3(1, 256), 256, 0, stream>>>(wtru, Bru[L], 0);
        // c = tanh(gconv([x|r*h]) Wc + bc);  h = u*h + (1-u)*c  (fused)
        concat_T<<<dim3(16, 32), 256, 0, stream>>>(xext, xoff, xbs, xd, Hoff, OFF_RU);
        dmfma_k<<<dim3(1, 8, 128), 256, 0, stream>>>();
        pgemm<64, 1><<<dim3(1, 256), 256, 0, stream>>>(wtc, Bc[L], Hoff);
    };

    // ---- encoder (stacked layers interleaved per timestep) ----
    for (int t = 0; t < 12; ++t) {
        cell(src + (long)t * 2048, -1, 24576, 2, OFF_H0, 0);
        cell(nullptr, OFF_H0, 65536, 64, OFF_H1, 1);
    }
    // ---- decoder (autoregressive, go token = zeros) ----
    for (int t = 0; t < 12; ++t) {
        const float* xp = t ? out + (long)(t - 1) * 32768 : (const float*)0;
        cell(xp, -1, 1024, 1, OFF_H0, 2);
        cell(nullptr, OFF_H0, 65536, 64, OFF_H1, 3);
        fcn_k<<<128, 256, 0, stream>>>(fcnW, fcnB, out + (long)t * 32768);
    }
}

// Round 11
// 7645.697 us; speedup vs baseline: 6.3386x; 1.4186x over previous
//
#include <hip/hip_runtime.h>

typedef unsigned short u16;
typedef __attribute__((ext_vector_type(4))) float f32x4;
typedef _Float16 f16x8 __attribute__((ext_vector_type(8)));
typedef __attribute__((ext_vector_type(8))) short short8;

// Static device workspace: 27,510,784 f32 = 110 MB. Module-owned; every
// meaningful region written before read on every call.
#define OFF_OPS   0L          // [4][1024][1024] f32: S0, 2S0^2-I, S1, 2S1^2-I
#define OFF_H0    4194304L    // [32*1024][64] f32
#define OFF_H1    6291456L    // [32*1024][64] f32
#define OFF_RSUM  8388608L    // [1024] f32
#define OFF_CSUM  8389632L    // [1024] f32
#define OFF_RU    8390656L    // [32*1024][128] f32
#define OFF_DH    12584960L   // u16: [32][1024][640] f16
#define OFF_OPSH  23070720L   // u16: [4][1024][1024] f16
#define OFF_XTH   25167872L   // u16: [32][128][1024] f16 (gate) / [32][64][1024] (rh)
#define OFF_WTH   27265024L   // u16: 4 x ([128][640] Wru^T | [64][640] Wc^T) f16
#define WS_TOTAL  27510784L

__device__ static float G_WS[WS_TOTAL];

__device__ __forceinline__ u16 f2h(float f) {
    return __builtin_bit_cast(u16, (_Float16)f);
}

__device__ __forceinline__ void gload_lds16(const void* g, void* l) {
    __builtin_amdgcn_global_load_lds((__attribute__((address_space(1))) void*)g,
                                     (__attribute__((address_space(3))) void*)l,
                                     16, 0, 0);
}

// zero H0,H1 (contiguous 4,194,304 from OFF_H0) and csum (1024)
__global__ __launch_bounds__(256)
void init0_k()
{
    const long i = (long)blockIdx.x * 256 + threadIdx.x;
    if (i < 4194304L) G_WS[OFF_H0 + i] = 0.f;
    else if (i < 4195328L) G_WS[OFF_CSUM + (i - 4194304L)] = 0.f;
}

// ---------------- f32 vector GEMM (P2 operator setup only, 2 dispatches) ---
template<bool P2F>
__global__ __launch_bounds__(256)
void sgemm(long Aoff, int lda, long Boff, int ldb, long Coff, int ldc, int K)
{
    __shared__ __attribute__((aligned(16))) float As[16][68];
    __shared__ __attribute__((aligned(16))) float Bs[16][68];
    const int tid = threadIdx.x;
    const int tm = tid & 15, tn = tid >> 4;
    const int m0 = blockIdx.y * 64, n0 = blockIdx.x * 64;
    const float* A = G_WS + Aoff;
    const float* B = G_WS + Boff;

    float acc[4][4] = {};
    const int arow = tid >> 2, akq = (tid & 3) * 4;
    const int brow = tid >> 4, bn4 = (tid & 15) * 4;

    for (int kt = 0; kt < K; kt += 16) {
        __syncthreads();
#pragma unroll
        for (int i = 0; i < 4; ++i)
            As[akq + i][arow] = A[(long)(m0 + arow) * lda + kt + akq + i];
#pragma unroll
        for (int i = 0; i < 4; ++i)
            Bs[brow][bn4 + i] = B[(long)(kt + brow) * ldb + n0 + bn4 + i];
        __syncthreads();
#pragma unroll
        for (int kk = 0; kk < 16; ++kk) {
            const f32x4 av = *(const f32x4*)&As[kk][tm * 4];
            const f32x4 bv = *(const f32x4*)&Bs[kk][tn * 4];
#pragma unroll
            for (int i = 0; i < 4; ++i)
#pragma unroll
                for (int j = 0; j < 4; ++j)
                    acc[i][j] += av[i] * bv[j];
        }
    }

    float* C = G_WS + Coff;
#pragma unroll
    for (int i = 0; i < 4; ++i)
#pragma unroll
        for (int j = 0; j < 4; ++j) {
            const int r = m0 + tm * 4 + i, c = n0 + tn * 4 + j;
            float v = acc[i][j];
            if (P2F) v = 2.f * v - (r == c ? 1.f : 0.f);
            C[(long)r * ldc + c] = v;
        }
}

// ---------------- f16 MFMA diffusion GEMM ----------------------------------
// Grid (1, 8, 128). XCD-bijective swizzle: lin = y + 8z; nw = (lin&7)*128 +
// (lin>>3); m-tile = nw&7, z' = nw>>3; mat = z'>>5, b = z'&31 — each XCD
// owns one operator x 16 batches (A 2MB + hot B slice, L2-resident).
// Writes DH[b][m][128 + mat*128 + colbase + c] for c in [0, BN).
template<int BN>
__global__ __launch_bounds__(256)
void dmfma_k(long btOff, long bstride, int colbase)
{
    constexpr int NF = BN / 32;
    __shared__ __attribute__((aligned(16))) u16 lds[(128 + BN) * 64];
    u16* ldsA = lds;
    u16* ldsB = lds + 128 * 64;

    const int tid = threadIdx.x, lane = tid & 63, wv = tid >> 6;
    const int lrow = lane & 15, lkq = lane >> 4;

    const int lin = blockIdx.y + 8 * (int)blockIdx.z;
    const int nw = (lin & 7) * 128 + (lin >> 3);
    const int m0 = (nw & 7) * 128;
    const int zp = nw >> 3;
    const int mat = zp >> 5, b = zp & 31;

    const u16* A  = (const u16*)(G_WS + OFF_OPSH) + (long)mat * 1048576L;
    const u16* Bt = (const u16*)(G_WS + btOff) + (long)b * bstride;
    const int wm = (wv >> 1) * 64, wn = (wv & 1) * (BN / 2);

    f32x4 acc[4][NF];
#pragma unroll
    for (int i = 0; i < 4; ++i)
#pragma unroll
        for (int j = 0; j < NF; ++j)
            acc[i][j] = f32x4{0.f, 0.f, 0.f, 0.f};

    for (int kt = 0; kt < 1024; kt += 64) {
        __syncthreads();
#pragma unroll
        for (int i = 0; i < 4; ++i) {
            const int ib = i * 4 + wv;                 // 0..15
            const int row = ib * 8 + (lane >> 3);
            const int c8 = lane & 7;
            gload_lds16(A + (long)(m0 + row) * 1024 + kt + c8 * 8, ldsA + ib * 512);
        }
#pragma unroll
        for (int i = 0; i < NF; ++i) {
            const int ib = i * 4 + wv;                 // 0..BN/8-1
            const int row = ib * 8 + (lane >> 3);
            const int c8 = lane & 7;
            gload_lds16(Bt + (long)row * 1024 + kt + c8 * 8, ldsB + ib * 512);
        }
        asm volatile("s_waitcnt vmcnt(0)" ::: "memory");
        __syncthreads();

#pragma unroll
        for (int kk = 0; kk < 2; ++kk) {
            f16x8 af[4];
#pragma unroll
            for (int mf = 0; mf < 4; ++mf)
                af[mf] = *(const f16x8*)(ldsA + (wm + mf * 16 + lrow) * 64 + kk * 32 + lkq * 8);
#pragma unroll
            for (int nf = 0; nf < NF; ++nf) {
                f16x8 bfv = *(const f16x8*)(ldsB + (wn + nf * 16 + lrow) * 64 + kk * 32 + lkq * 8);
#pragma unroll
                for (int mf = 0; mf < 4; ++mf)
                    acc[mf][nf] = __builtin_amdgcn_mfma_f32_16x16x32_f16(af[mf], bfv, acc[mf][nf], 0, 0, 0);
            }
        }
    }

    u16* Dp = (u16*)(G_WS + OFF_DH) + ((long)b * 1024 + m0) * 640 + 128 + mat * 128 + colbase;
#pragma unroll
    for (int mf = 0; mf < 4; ++mf)
#pragma unroll
        for (int nf = 0; nf < NF; ++nf)
#pragma unroll
            for (int j = 0; j < 4; ++j)
                Dp[(long)(wm + mf * 16 + lkq * 4 + j) * 640 + wn + nf * 16 + lrow] =
                    f2h(acc[mf][nf][j]);
}

// ---------------- f16 MFMA projection with fused epilogue -------------------
// A = DH [32768][640], B^T = WTH [N][640]. Grid y = 512 (64-row tiles).
// EPI 0: RU[gr][col] = sigmoid(acc + bias[col])           (BN=128)
// EPI 1: c=tanh(acc+bias); u=RU[gr][64+col]; H[gr][col]=u*H+(1-u)*c  (BN=64)
template<int BN, int EPI>
__global__ __launch_bounds__(256)
void pgemm(long WThoff, const float* __restrict__ bias, long Hoff)
{
    constexpr int NF = BN / 32;
    __shared__ __attribute__((aligned(16))) u16 lds[64 * 64 + BN * 64];
    u16* ldsA = lds;
    u16* ldsB = lds + 64 * 64;
    const u16* A  = (const u16*)(G_WS + OFF_DH);
    const u16* Bt = (const u16*)(G_WS + WThoff);

    const int tid = threadIdx.x, lane = tid & 63, wv = tid >> 6;
    const int lrow = lane & 15, lkq = lane >> 4;
    const int m0 = blockIdx.y * 64;
    const int wm = (wv & 1) * 32, wn = (wv >> 1) * (BN / 2);

    f32x4 acc[2][NF];
#pragma unroll
    for (int i = 0; i < 2; ++i)
#pragma unroll
        for (int j = 0; j < NF; ++j)
            acc[i][j] = f32x4{0.f, 0.f, 0.f, 0.f};

    for (int kt = 0; kt < 640; kt += 64) {
        __syncthreads();
#pragma unroll
        for (int i = 0; i < 2; ++i) {
            const int ib = i * 4 + wv;                 // 0..7
            const int row = ib * 8 + (lane >> 3);
            const int c8 = lane & 7;
            gload_lds16(A + (long)(m0 + row) * 640 + kt + c8 * 8, ldsA + ib * 512);
        }
#pragma unroll
        for (int i = 0; i < NF; ++i) {
            const int ib = i * 4 + wv;
            const int row = ib * 8 + (lane >> 3);
            const int c8 = lane & 7;
            gload_lds16(Bt + (long)row * 640 + kt + c8 * 8, ldsB + ib * 512);
        }
        asm volatile("s_waitcnt vmcnt(0)" ::: "memory");
        __syncthreads();

#pragma unroll
        for (int kk = 0; kk < 2; ++kk) {
            f16x8 af[2];
#pragma unroll
            for (int mf = 0; mf < 2; ++mf)
                af[mf] = *(const f16x8*)(ldsA + (wm + mf * 16 + lrow) * 64 + kk * 32 + lkq * 8);
#pragma unroll
            for (int nf = 0; nf < NF; ++nf) {
                f16x8 bfv = *(const f16x8*)(ldsB + (wn + nf * 16 + lrow) * 64 + kk * 32 + lkq * 8);
#pragma unroll
                for (int mf = 0; mf < 2; ++mf)
                    acc[mf][nf] = __builtin_amdgcn_mfma_f32_16x16x32_f16(af[mf], bfv, acc[mf][nf], 0, 0, 0);
            }
        }
    }

#pragma unroll
    for (int mf = 0; mf < 2; ++mf)
#pragma unroll
        for (int nf = 0; nf < NF; ++nf)
#pragma unroll
            for (int j = 0; j < 4; ++j) {
                const long gr = m0 + wm + mf * 16 + lkq * 4 + j;
                const int col = wn + nf * 16 + lrow;
                const float v = acc[mf][nf][j] + bias[col];
                if (EPI == 0) {
                    G_WS[OFF_RU + gr * 128 + col] = 1.f / (1.f + __expf(-v));
                } else {
                    const float c = tanhf(v);
                    const float u = G_WS[OFF_RU + gr * 128 + 64 + col];
                    float* hp = G_WS + Hoff + gr * 64 + col;
                    *hp = u * *hp + (1.f - u) * c;
                }
            }
}

// ---------------- fused concat + transpose (gate pass) ----------------------
// DH[b][n][0:128] = [x | h | 0-pad] (f16) and XTH[b][f][n] (f16, 128 rows).
__global__ __launch_bounds__(256)
void concat_T(const float* __restrict__ xext, long xoff, long xbs, int xd,
              long Hoff)
{
    const int nt = blockIdx.x, b = blockIdx.y;
    const int n0 = nt * 64;
    __shared__ u16 t[64][136];
    const int tid = threadIdx.x;
    const float* x = xext ? xext : (xoff >= 0 ? G_WS + xoff : (const float*)0);
    {
        const int nl = tid >> 2;
        const int cg = (tid & 3) * 32;
        const long gr = (long)b * 1024 + n0 + nl;
        const float* hrow = G_WS + Hoff + gr * 64;
        const float* xrow = x ? x + (long)b * xbs + (long)(n0 + nl) * xd : (const float*)0;
        alignas(16) u16 vals[32];
#pragma unroll
        for (int i = 0; i < 32; ++i) {
            const int f = cg + i;
            float v = 0.f;
            if (f < xd) { if (xrow) v = xrow[f]; }
            else if (f < xd + 64) v = hrow[f - xd];
            vals[i] = f2h(v);
        }
        u16* grow = (u16*)(G_WS + OFF_DH) + gr * 640 + cg;
#pragma unroll
        for (int i = 0; i < 32; i += 8) *(short8*)(grow + i) = *(const short8*)(vals + i);
#pragma unroll
        for (int i = 0; i < 32; ++i) t[nl][cg + i] = vals[i];
    }
    __syncthreads();
    {
        const int f = tid >> 1;
        const int nh = (tid & 1) * 32;
        alignas(16) u16 ov[32];
#pragma unroll
        for (int i = 0; i < 32; ++i) ov[i] = t[nh + i][f];
        u16* xt = (u16*)(G_WS + OFF_XTH) + ((long)b * 128 + f) * 1024 + n0 + nh;
#pragma unroll
        for (int i = 0; i < 32; i += 8) *(short8*)(xt + i) = *(const short8*)(ov + i);
    }
}

// ---------------- r*h update for the candidate pass -------------------------
// DH[b][n][xd .. xd+64) = r*h (f16)  and  XTHrh[b][f][n] ([32][64][1024]).
__global__ __launch_bounds__(256)
void rhT_k(int xd, long Hoff)
{
    const int nt = blockIdx.x, b = blockIdx.y;
    const int n0 = nt * 64;
    __shared__ u16 t[64][72];
    const int tid = threadIdx.x;
    {
        const int nl = tid >> 2;           // node 0..63
        const int cg = (tid & 3) * 16;     // feature group
        const long gr = (long)b * 1024 + n0 + nl;
        const float* hrow = G_WS + Hoff + gr * 64;
        const float* rrow = G_WS + OFF_RU + gr * 128;
        u16* drow = (u16*)(G_WS + OFF_DH) + gr * 640 + xd;
#pragma unroll
        for (int i = 0; i < 16; ++i) {
            const int f = cg + i;
            const u16 v = f2h(hrow[f] * rrow[f]);
            t[nl][f] = v;
            drow[f] = v;
        }
    }
    __syncthreads();
    {
        const int f = tid >> 2;            // feature 0..63
        const int ng = (tid & 3) * 16;     // node group
        alignas(16) u16 ov[16];
#pragma unroll
        for (int i = 0; i < 16; ++i) ov[i] = t[ng + i][f];
        u16* xt = (u16*)(G_WS + OFF_XTH) + ((long)b * 64 + f) * 1024 + n0 + ng;
#pragma unroll
        for (int i = 0; i < 16; i += 8) *(short8*)(xt + i) = *(const short8*)(ov + i);
    }
}

__global__ __launch_bounds__(256)
void rowsum_k(const float* __restrict__ adj)
{
    const int r = blockIdx.x, tid = threadIdx.x;
    float s = 0.f;
    for (int c = tid; c < 1024; c += 256) s += adj[(long)r * 1024 + c];
#pragma unroll
    for (int o = 32; o; o >>= 1) s += __shfl_down(s, o, 64);
    __shared__ float ps[4];
    if ((tid & 63) == 0) ps[tid >> 6] = s;
    __syncthreads();
    if (tid == 0) G_WS[OFF_RSUM + r] = ps[0] + ps[1] + ps[2] + ps[3];
}

__global__ __launch_bounds__(256)
void colsum_k(const float* __restrict__ adj)
{
    const int c = blockIdx.x * 256 + threadIdx.x;
    float s = 0.f;
    for (int r = 0; r < 1024; ++r) s += adj[(long)r * 1024 + c];
    G_WS[OFF_CSUM + c] = s;
}

// OPS[0][m][n]=adj[n][m]/rsum[n]  OPS[2][m][n]=adj[m][n]/csum[n]
__global__ __launch_bounds__(256)
void ops_k(const float* __restrict__ adj)
{
    const int id = blockIdx.x * 256 + threadIdx.x;
    const int m = id >> 10, n = id & 1023;
    G_WS[OFF_OPS + id] = adj[(long)n * 1024 + m] / fmaxf(G_WS[OFF_RSUM + n], 1e-8f);
    G_WS[OFF_OPS + 2 * 1048576L + id] = adj[id] / fmaxf(G_WS[OFF_CSUM + n], 1e-8f);
}

// OPS f32 -> OPSH f16
__global__ __launch_bounds__(256)
void opsh_k()
{
    const long i = (long)blockIdx.x * 256 + threadIdx.x;   // 16384 blocks
    ((u16*)(G_WS + OFF_OPSH))[i] = f2h(G_WS[OFF_OPS + i]);
}

// WTH[o][j] ([O][640] f16, K-contiguous) = (fp<F) ? W[(k*F+fp)*O+o] : 0
__global__ __launch_bounds__(256)
void wth_k(const float* __restrict__ W, long WThoff, int O, int F)
{
    const int id = blockIdx.x * 256 + threadIdx.x;
    if (id >= O * 640) return;
    const int o = id / 640, j = id % 640;
    const int k = j >> 7, fp = j & 127;
    ((u16*)(G_WS + WThoff))[id] = (fp < F) ? f2h(W[(long)(k * F + fp) * O + o]) : (u16)0;
}

__global__ __launch_bounds__(256)
void fcn_k(const float* __restrict__ W, const float* __restrict__ bp,
           float* __restrict__ out)
{
    __shared__ float w[64];
    __shared__ float bsh;
    const int tid = threadIdx.x;
    if (tid < 64) w[tid] = W[tid];
    if (tid == 64) bsh = bp[0];
    __syncthreads();
    const long r = (long)blockIdx.x * 256 + tid;
    float acc = bsh;
#pragma unroll
    for (int i = 0; i < 64; ++i) acc += G_WS[OFF_H1 + r * 64 + i] * w[i];
    out[r] = acc;
}

extern "C" void kernel_launch(void* const* d_in, const int* in_sizes, int n_in,
                              void* d_out, int out_size, void* d_ws, size_t ws_size,
                              hipStream_t stream)
{
    (void)in_sizes; (void)n_in; (void)out_size; (void)d_ws; (void)ws_size;

    const float* adj = (const float*)d_in[0];
    const float* src = (const float*)d_in[1];
    const float* Wru[4] = {(const float*)d_in[3], (const float*)d_in[7], (const float*)d_in[11], (const float*)d_in[15]};
    const float* Bru[4] = {(const float*)d_in[4], (const float*)d_in[8], (const float*)d_in[12], (const float*)d_in[16]};
    const float* Wc[4]  = {(const float*)d_in[5], (const float*)d_in[9], (const float*)d_in[13], (const float*)d_in[17]};
    const float* Bc[4]  = {(const float*)d_in[6], (const float*)d_in[10], (const float*)d_in[14], (const float*)d_in[18]};
    const float* fcnW = (const float*)d_in[19];
    const float* fcnB = (const float*)d_in[20];
    const int Fdim[4] = {66, 128, 65, 128};
    float* out = (float*)d_out;

    init0_k<<<16388, 256, 0, stream>>>();

    // ---- operators: M0=S0, M1=2*S0^2-I, M2=S1, M3=2*S1^2-I (f32) + f16 copy
    rowsum_k<<<1024, 256, 0, stream>>>(adj);
    colsum_k<<<4, 256, 0, stream>>>(adj);
    ops_k<<<4096, 256, 0, stream>>>(adj);
    sgemm<true><<<dim3(16, 16), 256, 0, stream>>>(
        OFF_OPS, 1024, OFF_OPS, 1024, OFF_OPS + 1048576L, 1024, 1024);
    sgemm<true><<<dim3(16, 16), 256, 0, stream>>>(
        OFF_OPS + 2097152L, 1024, OFF_OPS + 2097152L, 1024, OFF_OPS + 3145728L, 1024, 1024);
    opsh_k<<<16384, 256, 0, stream>>>();

    // ---- weight transforms (f16, K-contiguous [O][640]) ----
    for (int L = 0; L < 4; ++L) {
        wth_k<<<320, 256, 0, stream>>>(Wru[L], OFF_WTH + L * 61440L, 128, Fdim[L]);
        wth_k<<<160, 256, 0, stream>>>(Wc[L],  OFF_WTH + L * 61440L + 40960L, 64, Fdim[L]);
    }

    // one DCGRU cell (layer L), full batch (32); h at Hoff updated in place
    auto cell = [&](const float* xext, long xoff, long xbs, int xd, long Hoff, int L) {
        const long wtru = OFF_WTH + L * 61440L;
        const long wtc = wtru + 40960L;
        // ru = sigmoid(gconv([x|h]) Wru + bru)
        concat_T<<<dim3(16, 32), 256, 0, stream>>>(xext, xoff, xbs, xd, Hoff);
        if (Fdim[L] > 96)
            dmfma_k<128><<<dim3(1, 8, 128), 256, 0, stream>>>(OFF_XTH, 131072L, 0);
        else
            dmfma_k<96><<<dim3(1, 8, 128), 256, 0, stream>>>(OFF_XTH, 131072L, 0);
        pgemm<128, 0><<<dim3(1, 512), 256, 0, stream>>>(wtru, Bru[L], 0);
        // c = tanh(gconv([x|r*h]) Wc + bc);  h = u*h + (1-u)*c  (fused)
        // x-derived diffusion columns persist from the gate pass; only the
        // h-derived columns (r*h) are recomputed (BN=64).
        rhT_k<<<dim3(16, 32), 256, 0, stream>>>(xd, Hoff);
        dmfma_k<64><<<dim3(1, 8, 128), 256, 0, stream>>>(OFF_XTH, 65536L, xd);
        pgemm<64, 1><<<dim3(1, 512), 256, 0, stream>>>(wtc, Bc[L], Hoff);
    };

    // ---- encoder (stacked layers interleaved per timestep) ----
    for (int t = 0; t < 12; ++t) {
        cell(src + (long)t * 2048, -1, 24576, 2, OFF_H0, 0);
        cell(nullptr, OFF_H0, 65536, 64, OFF_H1, 1);
    }
    // ---- decoder (autoregressive, go token = zeros) ----
    for (int t = 0; t < 12; ++t) {
        const float* xp = t ? out + (long)(t - 1) * 32768 : (const float*)0;
        cell(xp, -1, 1024, 1, OFF_H0, 2);
        cell(nullptr, OFF_H0, 65536, 64, OFF_H1, 3);
        fcn_k<<<128, 256, 0, stream>>>(fcnW, fcnB, out + (long)t * 32768);
    }
}

// Round 12
// 7597.462 us; speedup vs baseline: 6.3788x; 1.0063x over previous
//
#include <hip/hip_runtime.h>

typedef unsigned short u16;
typedef __attribute__((ext_vector_type(4))) float f32x4;
typedef _Float16 f16x8 __attribute__((ext_vector_type(8)));
typedef __attribute__((ext_vector_type(8))) short short8;

// Static device workspace. Module-owned; every meaningful region written
// before read on every call.
#define OFF_OPS   0L          // [4][1024][1024] f32: S0, 2S0^2-I, S1, 2S1^2-I
#define OFF_H0    4194304L    // [32*1024][64] f32
#define OFF_H1    6291456L    // [32*1024][64] f32
#define OFF_RSUM  8388608L    // [1024] f32
#define OFF_CSUM  8389632L    // [1024] f32
#define OFF_RU    8390656L    // [32*1024][64] f32 (compact: u gate only)
#define OFF_DH    12584960L   // u16: [32][1024][640] f16
#define OFF_OPSH  23070720L   // u16: [4][1024][1024] f16
#define OFF_XTH   25167872L   // u16: [32][128][1024] f16 (gate) / [32][64][1024] (rh)
#define OFF_WTH   27265024L   // u16: 4 x ([128][640] Wru^T | [64][640] Wc^T) f16
#define WS_TOTAL  27510784L

__device__ static float G_WS[WS_TOTAL];

__device__ __forceinline__ u16 f2h(float f) {
    return __builtin_bit_cast(u16, (_Float16)f);
}

__device__ __forceinline__ void gload_lds16(const void* g, void* l) {
    __builtin_amdgcn_global_load_lds((__attribute__((address_space(1))) void*)g,
                                     (__attribute__((address_space(3))) void*)l,
                                     16, 0, 0);
}

// zero H0,H1 (contiguous 4,194,304 from OFF_H0) and csum (1024)
__global__ __launch_bounds__(256)
void init0_k()
{
    const long i = (long)blockIdx.x * 256 + threadIdx.x;
    if (i < 4194304L) G_WS[OFF_H0 + i] = 0.f;
    else if (i < 4195328L) G_WS[OFF_CSUM + (i - 4194304L)] = 0.f;
}

// ---------------- f32 vector GEMM (P2 operator setup only, 2 dispatches) ---
template<bool P2F>
__global__ __launch_bounds__(256)
void sgemm(long Aoff, int lda, long Boff, int ldb, long Coff, int ldc, int K)
{
    __shared__ __attribute__((aligned(16))) float As[16][68];
    __shared__ __attribute__((aligned(16))) float Bs[16][68];
    const int tid = threadIdx.x;
    const int tm = tid & 15, tn = tid >> 4;
    const int m0 = blockIdx.y * 64, n0 = blockIdx.x * 64;
    const float* A = G_WS + Aoff;
    const float* B = G_WS + Boff;

    float acc[4][4] = {};
    const int arow = tid >> 2, akq = (tid & 3) * 4;
    const int brow = tid >> 4, bn4 = (tid & 15) * 4;

    for (int kt = 0; kt < K; kt += 16) {
        __syncthreads();
#pragma unroll
        for (int i = 0; i < 4; ++i)
            As[akq + i][arow] = A[(long)(m0 + arow) * lda + kt + akq + i];
#pragma unroll
        for (int i = 0; i < 4; ++i)
            Bs[brow][bn4 + i] = B[(long)(kt + brow) * ldb + n0 + bn4 + i];
        __syncthreads();
#pragma unroll
        for (int kk = 0; kk < 16; ++kk) {
            const f32x4 av = *(const f32x4*)&As[kk][tm * 4];
            const f32x4 bv = *(const f32x4*)&Bs[kk][tn * 4];
#pragma unroll
            for (int i = 0; i < 4; ++i)
#pragma unroll
                for (int j = 0; j < 4; ++j)
                    acc[i][j] += av[i] * bv[j];
        }
    }

    float* C = G_WS + Coff;
#pragma unroll
    for (int i = 0; i < 4; ++i)
#pragma unroll
        for (int j = 0; j < 4; ++j) {
            const int r = m0 + tm * 4 + i, c = n0 + tn * 4 + j;
            float v = acc[i][j];
            if (P2F) v = 2.f * v - (r == c ? 1.f : 0.f);
            C[(long)r * ldc + c] = v;
        }
}

// ---------------- f16 MFMA diffusion GEMM ----------------------------------
// Grid (1, 8, 128). XCD-bijective swizzle: lin = y + 8z; nw = (lin&7)*128 +
// (lin>>3); m-tile = nw&7, z' = nw>>3; mat = z'>>5, b = z'&31 — each XCD
// owns one operator x 16 batches (A 2MB + hot B slice, L2-resident).
// Writes DH[b][m][128 + mat*128 + colbase + c] for c in [0, BN).
template<int BN>
__global__ __launch_bounds__(256)
void dmfma_k(long btOff, long bstride, int colbase)
{
    constexpr int NF = BN / 32;
    __shared__ __attribute__((aligned(16))) u16 lds[(128 + BN) * 64];
    u16* ldsA = lds;
    u16* ldsB = lds + 128 * 64;

    const int tid = threadIdx.x, lane = tid & 63, wv = tid >> 6;
    const int lrow = lane & 15, lkq = lane >> 4;

    const int lin = blockIdx.y + 8 * (int)blockIdx.z;
    const int nw = (lin & 7) * 128 + (lin >> 3);
    const int m0 = (nw & 7) * 128;
    const int zp = nw >> 3;
    const int mat = zp >> 5, b = zp & 31;

    const u16* A  = (const u16*)(G_WS + OFF_OPSH) + (long)mat * 1048576L;
    const u16* Bt = (const u16*)(G_WS + btOff) + (long)b * bstride;
    const int wm = (wv >> 1) * 64, wn = (wv & 1) * (BN / 2);

    f32x4 acc[4][NF];
#pragma unroll
    for (int i = 0; i < 4; ++i)
#pragma unroll
        for (int j = 0; j < NF; ++j)
            acc[i][j] = f32x4{0.f, 0.f, 0.f, 0.f};

    for (int kt = 0; kt < 1024; kt += 64) {
        __syncthreads();
#pragma unroll
        for (int i = 0; i < 4; ++i) {
            const int ib = i * 4 + wv;                 // 0..15
            const int row = ib * 8 + (lane >> 3);
            const int c8 = lane & 7;
            gload_lds16(A + (long)(m0 + row) * 1024 + kt + c8 * 8, ldsA + ib * 512);
        }
#pragma unroll
        for (int i = 0; i < NF; ++i) {
            const int ib = i * 4 + wv;                 // 0..BN/8-1
            const int row = ib * 8 + (lane >> 3);
            const int c8 = lane & 7;
            gload_lds16(Bt + (long)row * 1024 + kt + c8 * 8, ldsB + ib * 512);
        }
        asm volatile("s_waitcnt vmcnt(0)" ::: "memory");
        __syncthreads();

#pragma unroll
        for (int kk = 0; kk < 2; ++kk) {
            f16x8 af[4];
#pragma unroll
            for (int mf = 0; mf < 4; ++mf)
                af[mf] = *(const f16x8*)(ldsA + (wm + mf * 16 + lrow) * 64 + kk * 32 + lkq * 8);
#pragma unroll
            for (int nf = 0; nf < NF; ++nf) {
                f16x8 bfv = *(const f16x8*)(ldsB + (wn + nf * 16 + lrow) * 64 + kk * 32 + lkq * 8);
#pragma unroll
                for (int mf = 0; mf < 4; ++mf)
                    acc[mf][nf] = __builtin_amdgcn_mfma_f32_16x16x32_f16(af[mf], bfv, acc[mf][nf], 0, 0, 0);
            }
        }
    }

    u16* Dp = (u16*)(G_WS + OFF_DH) + ((long)b * 1024 + m0) * 640 + 128 + mat * 128 + colbase;
#pragma unroll
    for (int mf = 0; mf < 4; ++mf)
#pragma unroll
        for (int nf = 0; nf < NF; ++nf)
#pragma unroll
            for (int j = 0; j < 4; ++j)
                Dp[(long)(wm + mf * 16 + lkq * 4 + j) * 640 + wn + nf * 16 + lrow] =
                    f2h(acc[mf][nf][j]);
}

// ---------------- f16 MFMA projection with fused epilogue -------------------
// A = DH [32768][640], B^T = WTH [N][640]. Grid y = 512 (64-row tiles; one
// block's rows lie inside a single batch since 64 | 1024).
// EPI 0 (BN=128, gate): r=sig(acc+b) for col<64 -> rh=r*h written to
//   DH[gr][xd+col] and (via LDS transpose) XTH[b][col][n]; u=sig for col>=64
//   -> compact RU[gr*64+col-64]. This block reads DH only on its OWN rows, so
//   the in-place rh overwrite is race-free across blocks.
// EPI 1 (BN=64, GRU): c=tanh(acc+b); u=RU[gr*64+col]; H[gr][col]=u*H+(1-u)*c.
template<int BN, int EPI>
__global__ __launch_bounds__(256)
void pgemm(long WThoff, const float* __restrict__ bias, long Hoff, int xd)
{
    constexpr int NF = BN / 32;
    __shared__ __attribute__((aligned(16))) u16 lds[64 * 64 + BN * 64];
    u16* ldsA = lds;
    u16* ldsB = lds + 64 * 64;
    const u16* A  = (const u16*)(G_WS + OFF_DH);
    const u16* Bt = (const u16*)(G_WS + WThoff);

    const int tid = threadIdx.x, lane = tid & 63, wv = tid >> 6;
    const int lrow = lane & 15, lkq = lane >> 4;
    const int m0 = blockIdx.y * 64;
    const int wm = (wv & 1) * 32, wn = (wv >> 1) * (BN / 2);

    f32x4 acc[2][NF];
#pragma unroll
    for (int i = 0; i < 2; ++i)
#pragma unroll
        for (int j = 0; j < NF; ++j)
            acc[i][j] = f32x4{0.f, 0.f, 0.f, 0.f};

    for (int kt = 0; kt < 640; kt += 64) {
        __syncthreads();
#pragma unroll
        for (int i = 0; i < 2; ++i) {
            const int ib = i * 4 + wv;                 // 0..7
            const int row = ib * 8 + (lane >> 3);
            const int c8 = lane & 7;
            gload_lds16(A + (long)(m0 + row) * 640 + kt + c8 * 8, ldsA + ib * 512);
        }
#pragma unroll
        for (int i = 0; i < NF; ++i) {
            const int ib = i * 4 + wv;
            const int row = ib * 8 + (lane >> 3);
            const int c8 = lane & 7;
            gload_lds16(Bt + (long)row * 640 + kt + c8 * 8, ldsB + ib * 512);
        }
        asm volatile("s_waitcnt vmcnt(0)" ::: "memory");
        __syncthreads();

#pragma unroll
        for (int kk = 0; kk < 2; ++kk) {
            f16x8 af[2];
#pragma unroll
            for (int mf = 0; mf < 2; ++mf)
                af[mf] = *(const f16x8*)(ldsA + (wm + mf * 16 + lrow) * 64 + kk * 32 + lkq * 8);
#pragma unroll
            for (int nf = 0; nf < NF; ++nf) {
                f16x8 bfv = *(const f16x8*)(ldsB + (wn + nf * 16 + lrow) * 64 + kk * 32 + lkq * 8);
#pragma unroll
                for (int mf = 0; mf < 2; ++mf)
                    acc[mf][nf] = __builtin_amdgcn_mfma_f32_16x16x32_f16(af[mf], bfv, acc[mf][nf], 0, 0, 0);
            }
        }
    }

    if (EPI == 0) {
        __syncthreads();                   // all waves done reading LDS
        u16* t = ldsB;                     // reuse as [64][72] u16 (9 KB <= 16 KB)
        u16* DHp = (u16*)(G_WS + OFF_DH);
#pragma unroll
        for (int mf = 0; mf < 2; ++mf)
#pragma unroll
            for (int nf = 0; nf < NF; ++nf)
#pragma unroll
                for (int j = 0; j < 4; ++j) {
                    const int row = wm + mf * 16 + lkq * 4 + j;      // 0..63
                    const int col = wn + nf * 16 + lrow;             // 0..127
                    const long gr = m0 + row;
                    const float s = 1.f / (1.f + __expf(-(acc[mf][nf][j] + bias[col])));
                    if (col < 64) {
                        const float rh = s * G_WS[Hoff + gr * 64 + col];
                        const u16 hv = f2h(rh);
                        DHp[gr * 640 + xd + col] = hv;
                        t[row * 72 + col] = hv;
                    } else {
                        G_WS[OFF_RU + gr * 64 + (col - 64)] = s;
                    }
                }
        __syncthreads();
        // transpose t -> XTH[b][f][n] ([32][64][1024] layout for candidate dmfma)
        const int b = m0 >> 10, n0 = m0 & 1023;
        const int f = tid >> 2;
        const int ng = (tid & 3) * 16;
        alignas(16) u16 ov[16];
#pragma unroll
        for (int i = 0; i < 16; ++i) ov[i] = t[(ng + i) * 72 + f];
        u16* xt = (u16*)(G_WS + OFF_XTH) + ((long)b * 64 + f) * 1024 + n0 + ng;
#pragma unroll
        for (int i = 0; i < 16; i += 8) *(short8*)(xt + i) = *(const short8*)(ov + i);
    } else {
#pragma unroll
        for (int mf = 0; mf < 2; ++mf)
#pragma unroll
            for (int nf = 0; nf < NF; ++nf)
#pragma unroll
                for (int j = 0; j < 4; ++j) {
                    const long gr = m0 + wm + mf * 16 + lkq * 4 + j;
                    const int col = wn + nf * 16 + lrow;
                    const float c = tanhf(acc[mf][nf][j] + bias[col]);
                    const float u = G_WS[OFF_RU + gr * 64 + col];
                    float* hp = G_WS + Hoff + gr * 64 + col;
                    *hp = u * *hp + (1.f - u) * c;
                }
    }
}

// ---------------- fused concat + transpose (gate pass) ----------------------
// DH[b][n][0:128] = [x | h | 0-pad] (f16) and XTH[b][f][n] (f16, 128 rows).
__global__ __launch_bounds__(256)
void concat_T(const float* __restrict__ xext, long xoff, long xbs, int xd,
              long Hoff)
{
    const int nt = blockIdx.x, b = blockIdx.y;
    const int n0 = nt * 64;
    __shared__ u16 t[64][136];
    const int tid = threadIdx.x;
    const float* x = xext ? xext : (xoff >= 0 ? G_WS + xoff : (const float*)0);
    {
        const int nl = tid >> 2;
        const int cg = (tid & 3) * 32;
        const long gr = (long)b * 1024 + n0 + nl;
        const float* hrow = G_WS + Hoff + gr * 64;
        const float* xrow = x ? x + (long)b * xbs + (long)(n0 + nl) * xd : (const float*)0;
        alignas(16) u16 vals[32];
#pragma unroll
        for (int i = 0; i < 32; ++i) {
            const int f = cg + i;
            float v = 0.f;
            if (f < xd) { if (xrow) v = xrow[f]; }
            else if (f < xd + 64) v = hrow[f - xd];
            vals[i] = f2h(v);
        }
        u16* grow = (u16*)(G_WS + OFF_DH) + gr * 640 + cg;
#pragma unroll
        for (int i = 0; i < 32; i += 8) *(short8*)(grow + i) = *(const short8*)(vals + i);
#pragma unroll
        for (int i = 0; i < 32; ++i) t[nl][cg + i] = vals[i];
    }
    __syncthreads();
    {
        const int f = tid >> 1;
        const int nh = (tid & 1) * 32;
        alignas(16) u16 ov[32];
#pragma unroll
        for (int i = 0; i < 32; ++i) ov[i] = t[nh + i][f];
        u16* xt = (u16*)(G_WS + OFF_XTH) + ((long)b * 128 + f) * 1024 + n0 + nh;
#pragma unroll
        for (int i = 0; i < 32; i += 8) *(short8*)(xt + i) = *(const short8*)(ov + i);
    }
}

__global__ __launch_bounds__(256)
void rowsum_k(const float* __restrict__ adj)
{
    const int r = blockIdx.x, tid = threadIdx.x;
    float s = 0.f;
    for (int c = tid; c < 1024; c += 256) s += adj[(long)r * 1024 + c];
#pragma unroll
    for (int o = 32; o; o >>= 1) s += __shfl_down(s, o, 64);
    __shared__ float ps[4];
    if ((tid & 63) == 0) ps[tid >> 6] = s;
    __syncthreads();
    if (tid == 0) G_WS[OFF_RSUM + r] = ps[0] + ps[1] + ps[2] + ps[3];
}

__global__ __launch_bounds__(256)
void colsum_k(const float* __restrict__ adj)
{
    const int c = blockIdx.x * 256 + threadIdx.x;
    float s = 0.f;
    for (int r = 0; r < 1024; ++r) s += adj[(long)r * 1024 + c];
    G_WS[OFF_CSUM + c] = s;
}

// OPS[0][m][n]=adj[n][m]/rsum[n]  OPS[2][m][n]=adj[m][n]/csum[n]
__global__ __launch_bounds__(256)
void ops_k(const float* __restrict__ adj)
{
    const int id = blockIdx.x * 256 + threadIdx.x;
    const int m = id >> 10, n = id & 1023;
    G_WS[OFF_OPS + id] = adj[(long)n * 1024 + m] / fmaxf(G_WS[OFF_RSUM + n], 1e-8f);
    G_WS[OFF_OPS + 2 * 1048576L + id] = adj[id] / fmaxf(G_WS[OFF_CSUM + n], 1e-8f);
}

// OPS f32 -> OPSH f16
__global__ __launch_bounds__(256)
void opsh_k()
{
    const long i = (long)blockIdx.x * 256 + threadIdx.x;   // 16384 blocks
    ((u16*)(G_WS + OFF_OPSH))[i] = f2h(G_WS[OFF_OPS + i]);
}

// WTH[o][j] ([O][640] f16, K-contiguous) = (fp<F) ? W[(k*F+fp)*O+o] : 0
__global__ __launch_bounds__(256)
void wth_k(const float* __restrict__ W, long WThoff, int O, int F)
{
    const int id = blockIdx.x * 256 + threadIdx.x;
    if (id >= O * 640) return;
    const int o = id / 640, j = id % 640;
    const int k = j >> 7, fp = j & 127;
    ((u16*)(G_WS + WThoff))[id] = (fp < F) ? f2h(W[(long)(k * F + fp) * O + o]) : (u16)0;
}

__global__ __launch_bounds__(256)
void fcn_k(const float* __restrict__ W, const float* __restrict__ bp,
           float* __restrict__ out)
{
    __shared__ float w[64];
    __shared__ float bsh;
    const int tid = threadIdx.x;
    if (tid < 64) w[tid] = W[tid];
    if (tid == 64) bsh = bp[0];
    __syncthreads();
    const long r = (long)blockIdx.x * 256 + tid;
    float acc = bsh;
#pragma unroll
    for (int i = 0; i < 64; ++i) acc += G_WS[OFF_H1 + r * 64 + i] * w[i];
    out[r] = acc;
}

extern "C" void kernel_launch(void* const* d_in, const int* in_sizes, int n_in,
                              void* d_out, int out_size, void* d_ws, size_t ws_size,
                              hipStream_t stream)
{
    (void)in_sizes; (void)n_in; (void)out_size; (void)d_ws; (void)ws_size;

    const float* adj = (const float*)d_in[0];
    const float* src = (const float*)d_in[1];
    const float* Wru[4] = {(const float*)d_in[3], (const float*)d_in[7], (const float*)d_in[11], (const float*)d_in[15]};
    const float* Bru[4] = {(const float*)d_in[4], (const float*)d_in[8], (const float*)d_in[12], (const float*)d_in[16]};
    const float* Wc[4]  = {(const float*)d_in[5], (const float*)d_in[9], (const float*)d_in[13], (const float*)d_in[17]};
    const float* Bc[4]  = {(const float*)d_in[6], (const float*)d_in[10], (const float*)d_in[14], (const float*)d_in[18]};
    const float* fcnW = (const float*)d_in[19];
    const float* fcnB = (const float*)d_in[20];
    const int Fdim[4] = {66, 128, 65, 128};
    float* out = (float*)d_out;

    init0_k<<<16388, 256, 0, stream>>>();

    // ---- operators: M0=S0, M1=2*S0^2-I, M2=S1, M3=2*S1^2-I (f32) + f16 copy
    rowsum_k<<<1024, 256, 0, stream>>>(adj);
    colsum_k<<<4, 256, 0, stream>>>(adj);
    ops_k<<<4096, 256, 0, stream>>>(adj);
    sgemm<true><<<dim3(16, 16), 256, 0, stream>>>(
        OFF_OPS, 1024, OFF_OPS, 1024, OFF_OPS + 1048576L, 1024, 1024);
    sgemm<true><<<dim3(16, 16), 256, 0, stream>>>(
        OFF_OPS + 2097152L, 1024, OFF_OPS + 2097152L, 1024, OFF_OPS + 3145728L, 1024, 1024);
    opsh_k<<<16384, 256, 0, stream>>>();

    // ---- weight transforms (f16, K-contiguous [O][640]) ----
    for (int L = 0; L < 4; ++L) {
        wth_k<<<320, 256, 0, stream>>>(Wru[L], OFF_WTH + L * 61440L, 128, Fdim[L]);
        wth_k<<<160, 256, 0, stream>>>(Wc[L],  OFF_WTH + L * 61440L + 40960L, 64, Fdim[L]);
    }

    // one DCGRU cell (layer L), full batch (32); h at Hoff updated in place
    auto cell = [&](const float* xext, long xoff, long xbs, int xd, long Hoff, int L) {
        const long wtru = OFF_WTH + L * 61440L;
        const long wtc = wtru + 40960L;
        // ru-gate: sigmoid(gconv([x|h]) Wru + bru); epilogue also produces
        // rh -> DH identity slot + XTH (transposed) and compact u -> RU.
        concat_T<<<dim3(16, 32), 256, 0, stream>>>(xext, xoff, xbs, xd, Hoff);
        if (Fdim[L] > 96)
            dmfma_k<128><<<dim3(1, 8, 128), 256, 0, stream>>>(OFF_XTH, 131072L, 0);
        else
            dmfma_k<96><<<dim3(1, 8, 128), 256, 0, stream>>>(OFF_XTH, 131072L, 0);
        pgemm<128, 0><<<dim3(1, 512), 256, 0, stream>>>(wtru, Bru[L], Hoff, xd);
        // candidate: x-derived diffusion columns persist from the gate pass;
        // only the h-derived columns (r*h) are recomputed (BN=64).
        dmfma_k<64><<<dim3(1, 8, 128), 256, 0, stream>>>(OFF_XTH, 65536L, xd);
        pgemm<64, 1><<<dim3(1, 512), 256, 0, stream>>>(wtc, Bc[L], Hoff, 0);
    };

    // ---- encoder (stacked layers interleaved per timestep) ----
    for (int t = 0; t < 12; ++t) {
        cell(src + (long)t * 2048, -1, 24576, 2, OFF_H0, 0);
        cell(nullptr, OFF_H0, 65536, 64, OFF_H1, 1);
    }
    // ---- decoder (autoregressive, go token = zeros) ----
    for (int t = 0; t < 12; ++t) {
        const float* xp = t ? out + (long)(t - 1) * 32768 : (const float*)0;
        cell(xp, -1, 1024, 1, OFF_H0, 2);
        cell(nullptr, OFF_H0, 65536, 64, OFF_H1, 3);
        fcn_k<<<128, 256, 0, stream>>>(fcnW, fcnB, out + (long)t * 32768);
    }
}